// Round 11
// baseline (295.178 us; speedup 1.0000x reference)
//
#include <hip/hip_runtime.h>
#include <hip/hip_bf16.h>
#include <stdint.h>

typedef __attribute__((ext_vector_type(8))) short short8;
typedef __attribute__((ext_vector_type(4))) short short4v;
typedef __attribute__((ext_vector_type(4))) float f32x4;
typedef __attribute__((ext_vector_type(2))) float f32x2;

#define MFMA16x16x32(A, B, C) __builtin_amdgcn_mfma_f32_16x16x32_bf16((A), (B), (C), 0, 0, 0)

static constexpr int kS  = 2048;   // sequence length
static constexpr int kD  = 1024;   // d_model
static constexpr int kDK = 64;     // head dim

// ws layout, bf16 element offsets (total 64 MB)
static constexpr size_t OFF_XQ  = 0;          // dead after qkv_gemm -> partp + rinvp
static constexpr size_t OFF_XK  = 4194304;    // dead after qkv_gemm -> partial ctx (8.4M bf16)
static constexpr size_t OFF_XV  = 8388608;
static constexpr size_t OFF_W   = 12582912;   // Wq,Wk,Wv,Wo each 1048576
static constexpr size_t OFF_QP  = 16777216;   // [bh][s][d] (pre-scaled by 1/8)
static constexpr size_t OFF_KP  = 20971520;   // [bh][s][d]
static constexpr size_t OFF_VT  = 25165824;   // [bh][d][s]  (transposed)
static constexpr size_t OFF_CTX = 29360128;   // [b][s][h*64+d]

__device__ __forceinline__ short f2bf(float f) {
  __hip_bfloat16 h = __float2bfloat16(f);
  return *reinterpret_cast<short*>(&h);
}

__device__ __forceinline__ float bf2f(short s) {
  union { unsigned u; float f; } cv;
  cv.u = ((unsigned)(unsigned short)s) << 16;
  return cv.f;
}

// ---------------- fp32 -> bf16 convert ----------------
__global__ __launch_bounds__(256) void cvt_kernel(
    const float* __restrict__ xq, const float* __restrict__ xk, const float* __restrict__ xv,
    const float* __restrict__ wq, const float* __restrict__ wk, const float* __restrict__ wv,
    const float* __restrict__ wo, __hip_bfloat16* __restrict__ dst)
{
  int g = blockIdx.x * 256 + threadIdx.x;   // group of 4 floats
  const float* src;
  __hip_bfloat16* d;
  int rel;
  if (g < 3145728) {                // 3 inputs, 1048576 groups each
    int seg = g >> 20; rel = g & 1048575;
    src = seg == 0 ? xq : (seg == 1 ? xk : xv);
    d = dst + (size_t)seg * 4194304;
  } else {                          // 4 weights, 262144 groups each
    int g2 = g - 3145728; int seg = g2 >> 18; rel = g2 & 262143;
    src = seg == 0 ? wq : (seg == 1 ? wk : (seg == 2 ? wv : wo));
    d = dst + OFF_W + (size_t)seg * 1048576;
  }
  float4 v = ((const float4*)src)[rel];
  short4v o;
  o.x = f2bf(v.x); o.y = f2bf(v.y); o.z = f2bf(v.z); o.w = f2bf(v.w);
  ((short4v*)d)[rel] = o;
}

// ---------------- GEMM core: Y[128,128] = X[128,K] * W[128,K]^T ----------------
__device__ __forceinline__ void stage_tile(short* lds, const __hip_bfloat16* g0, int t) {
  #pragma unroll
  for (int c = 0; c < 2; ++c) {
    const int e = t * 8 + c * 2048;
    const int row = e >> 5;
    const int kk = e & 31;
    __builtin_amdgcn_global_load_lds(
        (const __attribute__((address_space(1))) void*)(g0 + (size_t)row * kD + kk),
        (__attribute__((address_space(3))) void*)(lds + e), 16, 0, 0);
  }
}

__device__ __forceinline__ void gemm_main(const __hip_bfloat16* X, const __hip_bfloat16* W,
                                          short* As, short* Bs, f32x4 acc[4][4])
{
  const int t = threadIdx.x;
  const int lane = t & 63;
  const int wv = t >> 6;
  const int wr = wv >> 1, wc = wv & 1;
  const int fr = lane & 15;
  const int fc = (lane >> 4) * 8;
  for (int k0 = 0; k0 < kD; k0 += 32) {
    stage_tile(As, X + k0, t);
    stage_tile(Bs, W + k0, t);
    __syncthreads();
    short8 af[4], bfv[4];
    #pragma unroll
    for (int i = 0; i < 4; ++i) af[i]  = *(const short8*)&As[(wr * 64 + i * 16 + fr) * 32 + fc];
    #pragma unroll
    for (int i = 0; i < 4; ++i) bfv[i] = *(const short8*)&Bs[(wc * 64 + i * 16 + fr) * 32 + fc];
    #pragma unroll
    for (int i = 0; i < 4; ++i)
      #pragma unroll
      for (int j = 0; j < 4; ++j)
        acc[i][j] = MFMA16x16x32(af[i], bfv[j], acc[i][j]);
    __syncthreads();
  }
}

// ---------------- QKV projection GEMM (z = 0:Q, 1:K, 2:V) ----------------
__global__ __launch_bounds__(256) void qkv_gemm(
    const __hip_bfloat16* __restrict__ Xq, const __hip_bfloat16* __restrict__ Xk,
    const __hip_bfloat16* __restrict__ Xv, const __hip_bfloat16* __restrict__ Wbase,
    const float* __restrict__ bq, const float* __restrict__ bk, const float* __restrict__ bv,
    __hip_bfloat16* __restrict__ Qp, __hip_bfloat16* __restrict__ Kp,
    __hip_bfloat16* __restrict__ Vt)
{
  __shared__ __align__(16) short As[128 * 32];
  __shared__ __align__(16) short Bs[128 * 32];
  const int z  = blockIdx.z;
  const int m0 = blockIdx.y * 128, n0 = blockIdx.x * 128;
  const __hip_bfloat16* X = (z == 0 ? Xq : (z == 1 ? Xk : Xv)) + (size_t)m0 * kD;
  const __hip_bfloat16* W = Wbase + (size_t)z * (kD * kD) + (size_t)n0 * kD;
  const float* bias = (z == 0 ? bq : (z == 1 ? bk : bv));
  f32x4 acc[4][4] = {};
  gemm_main(X, W, As, Bs, acc);

  const int lane = threadIdx.x & 63;
  const int wv = threadIdx.x >> 6;
  const int wr = wv >> 1, wc = wv & 1;
  short* dstQK = (short*)(z == 0 ? Qp : Kp);
  short* dstV  = (short*)Vt;
  #pragma unroll
  for (int i = 0; i < 4; ++i) {
    #pragma unroll
    for (int j = 0; j < 4; ++j) {
      #pragma unroll
      for (int r = 0; r < 4; ++r) {
        int m = m0 + wr * 64 + i * 16 + (lane >> 4) * 4 + r;
        int n = n0 + wc * 64 + j * 16 + (lane & 15);
        float y = acc[i][j][r] + bias[n];
        if (z == 0) y *= 0.125f;   // fold 1/sqrt(dk) into Q
        int b = m >> 11, sq = m & 2047, h = n >> 6, d = n & 63;
        if (z < 2)
          dstQK[((size_t)(b * 16 + h) * kS + sq) * kDK + d] = f2bf(y);
        else
          dstV[((size_t)(b * 16 + h) * kDK + d) * kS + sq] = f2bf(y);
      }
    }
  }
}

// ---------------- attention pass 1 (split-K): partial ctx + partial row-sums ----
// R8 structure (BK=32, LDS-staged K/V dbuf, swapped QK^T, per-wave Ps transpose),
// k-range halved per block -> grid 2048 -> 7 blocks/CU (~28 waves, was 16).
// Outputs UNNORMALIZED: ctxp[bh*2+ksg][q][d] (bf16) + partp[bh*2+ksg][q] (f32).
__global__ __launch_bounds__(256) void attn_pass1_split(
    const __hip_bfloat16* __restrict__ Qp, const __hip_bfloat16* __restrict__ Kp,
    const __hip_bfloat16* __restrict__ Vt, __hip_bfloat16* __restrict__ ctxp,
    float* __restrict__ partp)
{
  __shared__ __align__(16) short Ks[2][32][68];   // [kt-row][dk], pad 68
  __shared__ __align__(16) short Vs[2][64][36];   // [d][kt-col], pad 36
  __shared__ __align__(16) short Ps[4][16][36];   // per-wave P [q][k], pad 36
  const int t = threadIdx.x;
  const int lane = t & 63;
  const int w = t >> 6;
  const int fr = lane & 15;
  const int g4 = lane >> 4;
  const int fc = g4 * 8;

  const int id  = blockIdx.x;
  const int swz = (id & 7) * 256 + (id >> 3);   // XCD-contiguous (4 heads/XCD)
  const int bh  = swz >> 6;
  const int ksg = (swz >> 5) & 1;
  const int q0  = (swz & 31) * 64 + w * 16;
  const int kbase = ksg << 10;                  // 1024 k per segment

  const __hip_bfloat16* Qh = Qp + (size_t)bh * kS * kDK;
  const __hip_bfloat16* Kh = Kp + (size_t)bh * kS * kDK;
  const __hip_bfloat16* Vh = Vt + (size_t)bh * kDK * kS;

  const short8 qf0 = *(const short8*)(Qh + (size_t)(q0 + fr) * kDK + fc);
  const short8 qf1 = *(const short8*)(Qh + (size_t)(q0 + fr) * kDK + 32 + fc);

  // staging thread mapping
  const int kr = t >> 3, kc = (t & 7) * 8;      // K: 32 rows x 64 cols
  const int vr = t >> 2, vc = (t & 3) * 8;      // V: 64 rows x 32 cols

  f32x4 ctxacc[4] = {};
  float ssumq = 0.f;                            // partial row-sum for q = fr

  short8 kA, vA, kB, vB;

#define LOAD_T(KREG, VREG, TI)                                                   \
  KREG = *(const short8*)(Kh + (size_t)(kbase + (TI) * 32 + kr) * kDK + kc);     \
  VREG = *(const short8*)(Vh + (size_t)vr * kS + kbase + (TI) * 32 + vc);

#define STORE_T(KREG, VREG, BUF)                                                 \
  *(short8*)&Ks[BUF][kr][kc] = KREG;                                             \
  *(short8*)&Vs[BUF][vr][vc] = VREG;

#define COMPUTE_T(BUF)                                                           \
  {                                                                              \
    short8 k0a = *(const short8*)&Ks[BUF][fr][fc];                               \
    short8 k0b = *(const short8*)&Ks[BUF][fr][32 + fc];                          \
    short8 k1a = *(const short8*)&Ks[BUF][16 + fr][fc];                          \
    short8 k1b = *(const short8*)&Ks[BUF][16 + fr][32 + fc];                     \
    f32x4 s0 = {}; s0 = MFMA16x16x32(k0a, qf0, s0); s0 = MFMA16x16x32(k0b, qf1, s0); \
    f32x4 s1 = {}; s1 = MFMA16x16x32(k1a, qf0, s1); s1 = MFMA16x16x32(k1b, qf1, s1); \
    float e00 = __expf(s0[0]), e01 = __expf(s0[1]);                              \
    float e02 = __expf(s0[2]), e03 = __expf(s0[3]);                              \
    float e10 = __expf(s1[0]), e11 = __expf(s1[1]);                              \
    float e12 = __expf(s1[2]), e13 = __expf(s1[3]);                              \
    ssumq += (e00 + e01) + (e02 + e03) + (e10 + e11) + (e12 + e13);              \
    short4v p0, p1;                                                              \
    p0.x = f2bf(e00); p0.y = f2bf(e01); p0.z = f2bf(e02); p0.w = f2bf(e03);      \
    p1.x = f2bf(e10); p1.y = f2bf(e11); p1.z = f2bf(e12); p1.w = f2bf(e13);      \
    *(short4v*)&Ps[w][fr][g4 * 4]      = p0;                                     \
    *(short4v*)&Ps[w][fr][16 + g4 * 4] = p1;                                     \
    short8 pf = *(const short8*)&Ps[w][fr][fc];                                  \
    _Pragma("unroll")                                                            \
    for (int dc = 0; dc < 4; ++dc) {                                             \
      short8 vf = *(const short8*)&Vs[BUF][dc * 16 + fr][fc];                    \
      ctxacc[dc] = MFMA16x16x32(pf, vf, ctxacc[dc]);                             \
    }                                                                            \
  }

  // prologue (32 local tiles of 32 k)
  LOAD_T(kA, vA, 0);
  STORE_T(kA, vA, 0);
  LOAD_T(kB, vB, 1);
  __syncthreads();

  for (int i = 0; i < 32; i += 2) {
    COMPUTE_T(0);                       // tile i
    STORE_T(kB, vB, 1);                 // tile i+1
    if (i + 2 < 32) { LOAD_T(kA, vA, i + 2); }
    __syncthreads();
    COMPUTE_T(1);                       // tile i+1
    if (i + 2 < 32) { STORE_T(kA, vA, 0); }
    if (i + 3 < 32) { LOAD_T(kB, vB, i + 3); }
    __syncthreads();
  }

  // partial row-sum for q = fr: butterfly across the 4 g4 groups
  float s = ssumq;
  s += __shfl_xor(s, 16);
  s += __shfl_xor(s, 32);
  if (g4 == 0) partp[((size_t)bh * 2 + ksg) * kS + q0 + fr] = s;

  // unnormalized partial ctx -> scratch (bf16)
  short* cp = (short*)ctxp;
  #pragma unroll
  for (int dc = 0; dc < 4; ++dc) {
    #pragma unroll
    for (int j = 0; j < 4; ++j) {
      int r = g4 * 4 + j;
      cp[(((size_t)bh * 2 + ksg) * kS + q0 + r) * kDK + dc * 16 + fr] = f2bf(ctxacc[dc][j]);
    }
  }
#undef LOAD_T
#undef STORE_T
#undef COMPUTE_T
}

// ---------------- ctx reduction: combine k-halves, normalize, emit rinv ----------
__global__ __launch_bounds__(256) void reduce_ctx(
    const __hip_bfloat16* __restrict__ ctxp, const float* __restrict__ partp,
    __hip_bfloat16* __restrict__ Ctx, float* __restrict__ rinvp)
{
  const int idx = blockIdx.x * 256 + threadIdx.x;   // 1,048,576 threads
  const int d16 = idx & 15;                          // 4-elem d group
  const int q   = (idx >> 4) & 2047;
  const int bh  = idx >> 15;

  const float rv = 1.0f / (partp[(size_t)bh * 2 * kS + q] +
                           partp[((size_t)bh * 2 + 1) * kS + q]);

  const short* c0 = (const short*)ctxp + ((size_t)bh * 2 * kS + q) * kDK + d16 * 4;
  const short* c1 = (const short*)ctxp + (((size_t)bh * 2 + 1) * kS + q) * kDK + d16 * 4;
  short4v a = *(const short4v*)c0;
  short4v b2 = *(const short4v*)c1;
  short4v o;
  #pragma unroll
  for (int j = 0; j < 4; ++j) {
    float v = (bf2f(a[j]) + bf2f(b2[j])) * rv;
    o[j] = f2bf(v);
  }
  const int b = bh >> 4, h = bh & 15;
  *(short4v*)((short*)Ctx + ((size_t)(b * kS + q)) * kD + h * kDK + d16 * 4) = o;
  if (d16 == 0) rinvp[(size_t)bh * kS + q] = rv;
}

// ---------------- fused tail: o_gemm (blocks 0..255) + pass2 (blocks 256..4351)
__global__ __launch_bounds__(256) void fused_tail(
    const __hip_bfloat16* __restrict__ Ctx, const __hip_bfloat16* __restrict__ Wo,
    const float* __restrict__ bo, float* __restrict__ out,
    const __hip_bfloat16* __restrict__ Qp, const __hip_bfloat16* __restrict__ Kp,
    const float* __restrict__ rinvp, float* __restrict__ Aw)
{
  __shared__ __align__(16) short As[128 * 32];
  __shared__ __align__(16) short Bs[128 * 32];
  const int t = threadIdx.x;
  const int lane = t & 63;
  const int w = t >> 6;
  const int fr = lane & 15;
  const int g4 = lane >> 4;
  const int fc = g4 * 8;

  if (blockIdx.x < 256) {
    // ---- o_gemm ----
    const int m0 = (blockIdx.x >> 3) * 128, n0 = (blockIdx.x & 7) * 128;
    f32x4 acc[4][4] = {};
    gemm_main(Ctx + (size_t)m0 * kD, Wo + (size_t)n0 * kD, As, Bs, acc);
    const int wr = w >> 1, wc = w & 1;
    #pragma unroll
    for (int i = 0; i < 4; ++i) {
      #pragma unroll
      for (int j = 0; j < 4; ++j) {
        #pragma unroll
        for (int r = 0; r < 4; ++r) {
          int m = m0 + wr * 64 + i * 16 + g4 * 4 + r;
          int n = n0 + wc * 64 + j * 16 + fr;
          __builtin_nontemporal_store(acc[i][j][r] + bo[n], &out[(size_t)m * kD + n]);
        }
      }
    }
    return;
  }

  // ---- pass2: recompute scores (swapped operands), direct C-fragment stores ----
  const int id  = blockIdx.x - 256;
  const int swz = (id & 7) * 512 + (id >> 3);
  const int bh  = swz >> 7;
  const int ksg = (swz >> 5) & 3;
  const int q0  = (swz & 31) * 64 + w * 16;
  const int k0  = ksg * 512;

  const __hip_bfloat16* Qh = Qp + (size_t)bh * kS * kDK;
  const __hip_bfloat16* Kh = Kp + (size_t)bh * kS * kDK;

  const short8 qf0 = *(const short8*)(Qh + (size_t)(q0 + fr) * kDK + fc);
  const short8 qf1 = *(const short8*)(Qh + (size_t)(q0 + fr) * kDK + 32 + fc);

  const float rvq = rinvp[(size_t)bh * kS + q0 + fr];       // this lane's q-row
  float* aw = Aw + ((size_t)bh * kS + q0 + fr) * kS;        // row base

  short8 ka[8], kb[8];

#define LOADK(ARR, KT_)                                                          \
  _Pragma("unroll")                                                              \
  for (int c = 0; c < 4; ++c) {                                                  \
    ARR[2 * c]     = *(const short8*)(Kh + (size_t)((KT_) + c * 16 + fr) * kDK + fc);      \
    ARR[2 * c + 1] = *(const short8*)(Kh + (size_t)((KT_) + c * 16 + fr) * kDK + 32 + fc); \
  }

#define CSTORE(ARR, KT_)                                                         \
  _Pragma("unroll")                                                              \
  for (int c = 0; c < 4; ++c) {                                                  \
    f32x4 st = {};                                                               \
    st = MFMA16x16x32(ARR[2 * c], qf0, st);                                      \
    st = MFMA16x16x32(ARR[2 * c + 1], qf1, st);                                  \
    f32x4 v;                                                                     \
    _Pragma("unroll")                                                            \
    for (int j = 0; j < 4; ++j) v[j] = __expf(st[j]) * rvq;                      \
    __builtin_nontemporal_store(v, (f32x4*)(aw + (KT_) + c * 16 + g4 * 4));      \
  }

  LOADK(ka, k0);
  for (int kt = k0; kt < k0 + 512; kt += 128) {
    LOADK(kb, kt + 64);
    CSTORE(ka, kt);
    if (kt + 128 < k0 + 512) { LOADK(ka, kt + 128); }
    CSTORE(kb, kt + 64);
  }
#undef LOADK
#undef CSTORE
}

extern "C" void kernel_launch(void* const* d_in, const int* in_sizes, int n_in,
                              void* d_out, int out_size, void* d_ws, size_t ws_size,
                              hipStream_t stream) {
  (void)in_sizes; (void)n_in; (void)out_size; (void)ws_size;
  const float* Qin = (const float*)d_in[0];
  const float* Kin = (const float*)d_in[1];
  const float* Vin = (const float*)d_in[2];
  const float* Wq  = (const float*)d_in[3];
  const float* bq  = (const float*)d_in[4];
  const float* Wk  = (const float*)d_in[5];
  const float* bk  = (const float*)d_in[6];
  const float* Wv  = (const float*)d_in[7];
  const float* bv  = (const float*)d_in[8];
  const float* Wo  = (const float*)d_in[9];
  const float* bo  = (const float*)d_in[10];
  __hip_bfloat16* ws = (__hip_bfloat16*)d_ws;
  float* out = (float*)d_out;
  float* partp = (float*)(ws + OFF_XQ);          // 512 KB in dead XQ region
  float* rinvp = partp + 131072;                 // after partp, still in XQ region
  __hip_bfloat16* ctxp = ws + OFF_XK;            // 16.8 MB in dead XK+XV regions

  cvt_kernel<<<16384, 256, 0, stream>>>(Qin, Kin, Vin, Wq, Wk, Wv, Wo, ws);
  qkv_gemm<<<dim3(8, 32, 3), 256, 0, stream>>>(
      ws + OFF_XQ, ws + OFF_XK, ws + OFF_XV, ws + OFF_W, bq, bk, bv,
      ws + OFF_QP, ws + OFF_KP, ws + OFF_VT);
  attn_pass1_split<<<2048, 256, 0, stream>>>(
      ws + OFF_QP, ws + OFF_KP, ws + OFF_VT, ctxp, partp);
  reduce_ctx<<<4096, 256, 0, stream>>>(ctxp, partp, ws + OFF_CTX, rinvp);
  fused_tail<<<4352, 256, 0, stream>>>(
      ws + OFF_CTX, ws + OFF_W + 3 * 1048576, bo, out,
      ws + OFF_QP, ws + OFF_KP, rinvp, out + 4194304);
}

// Round 12
// 290.340 us; speedup vs baseline: 1.0167x; 1.0167x over previous
//
#include <hip/hip_runtime.h>
#include <hip/hip_bf16.h>
#include <stdint.h>

typedef __attribute__((ext_vector_type(8))) short short8;
typedef __attribute__((ext_vector_type(4))) short short4v;
typedef __attribute__((ext_vector_type(4))) float f32x4;
typedef __attribute__((ext_vector_type(2))) float f32x2;

#define MFMA16x16x32(A, B, C) __builtin_amdgcn_mfma_f32_16x16x32_bf16((A), (B), (C), 0, 0, 0)

static constexpr int kS  = 2048;   // sequence length
static constexpr int kD  = 1024;   // d_model
static constexpr int kDK = 64;     // head dim

// ws layout, bf16 element offsets (total 64 MB)
static constexpr size_t OFF_XQ  = 0;          // dead after qkv_gemm -> reused for rinv
static constexpr size_t OFF_XK  = 4194304;
static constexpr size_t OFF_XV  = 8388608;
static constexpr size_t OFF_W   = 12582912;   // Wq,Wk,Wv,Wo each 1048576
static constexpr size_t OFF_QP  = 16777216;   // [bh][s][d] (pre-scaled by 1/8)
static constexpr size_t OFF_KP  = 20971520;   // [bh][s][d]
static constexpr size_t OFF_VT  = 25165824;   // [bh][d][s]  (transposed)
static constexpr size_t OFF_CTX = 29360128;   // [b][s][h*64+d]

__device__ __forceinline__ short f2bf(float f) {
  __hip_bfloat16 h = __float2bfloat16(f);
  return *reinterpret_cast<short*>(&h);
}

// ---------------- fp32 -> bf16 convert ----------------
__global__ __launch_bounds__(256) void cvt_kernel(
    const float* __restrict__ xq, const float* __restrict__ xk, const float* __restrict__ xv,
    const float* __restrict__ wq, const float* __restrict__ wk, const float* __restrict__ wv,
    const float* __restrict__ wo, __hip_bfloat16* __restrict__ dst)
{
  int g = blockIdx.x * 256 + threadIdx.x;   // group of 4 floats
  const float* src;
  __hip_bfloat16* d;
  int rel;
  if (g < 3145728) {                // 3 inputs, 1048576 groups each
    int seg = g >> 20; rel = g & 1048575;
    src = seg == 0 ? xq : (seg == 1 ? xk : xv);
    d = dst + (size_t)seg * 4194304;
  } else {                          // 4 weights, 262144 groups each
    int g2 = g - 3145728; int seg = g2 >> 18; rel = g2 & 262143;
    src = seg == 0 ? wq : (seg == 1 ? wk : (seg == 2 ? wv : wo));
    d = dst + OFF_W + (size_t)seg * 1048576;
  }
  float4 v = ((const float4*)src)[rel];
  short4v o;
  o.x = f2bf(v.x); o.y = f2bf(v.y); o.z = f2bf(v.z); o.w = f2bf(v.w);
  ((short4v*)d)[rel] = o;
}

// ---------------- GEMM core: Y[128,128] = X[128,K] * W[128,K]^T ----------------
__device__ __forceinline__ void stage_tile(short* lds, const __hip_bfloat16* g0, int t) {
  #pragma unroll
  for (int c = 0; c < 2; ++c) {
    const int e = t * 8 + c * 2048;
    const int row = e >> 5;
    const int kk = e & 31;
    __builtin_amdgcn_global_load_lds(
        (const __attribute__((address_space(1))) void*)(g0 + (size_t)row * kD + kk),
        (__attribute__((address_space(3))) void*)(lds + e), 16, 0, 0);
  }
}

__device__ __forceinline__ void gemm_main(const __hip_bfloat16* X, const __hip_bfloat16* W,
                                          short* As, short* Bs, f32x4 acc[4][4])
{
  const int t = threadIdx.x;
  const int lane = t & 63;
  const int wv = t >> 6;
  const int wr = wv >> 1, wc = wv & 1;
  const int fr = lane & 15;
  const int fc = (lane >> 4) * 8;
  for (int k0 = 0; k0 < kD; k0 += 32) {
    stage_tile(As, X + k0, t);
    stage_tile(Bs, W + k0, t);
    __syncthreads();
    short8 af[4], bfv[4];
    #pragma unroll
    for (int i = 0; i < 4; ++i) af[i]  = *(const short8*)&As[(wr * 64 + i * 16 + fr) * 32 + fc];
    #pragma unroll
    for (int i = 0; i < 4; ++i) bfv[i] = *(const short8*)&Bs[(wc * 64 + i * 16 + fr) * 32 + fc];
    #pragma unroll
    for (int i = 0; i < 4; ++i)
      #pragma unroll
      for (int j = 0; j < 4; ++j)
        acc[i][j] = MFMA16x16x32(af[i], bfv[j], acc[i][j]);
    __syncthreads();
  }
}

// ---------------- QKV projection GEMM (z = 0:Q, 1:K, 2:V) ----------------
__global__ __launch_bounds__(256) void qkv_gemm(
    const __hip_bfloat16* __restrict__ Xq, const __hip_bfloat16* __restrict__ Xk,
    const __hip_bfloat16* __restrict__ Xv, const __hip_bfloat16* __restrict__ Wbase,
    const float* __restrict__ bq, const float* __restrict__ bk, const float* __restrict__ bv,
    __hip_bfloat16* __restrict__ Qp, __hip_bfloat16* __restrict__ Kp,
    __hip_bfloat16* __restrict__ Vt)
{
  __shared__ __align__(16) short As[128 * 32];
  __shared__ __align__(16) short Bs[128 * 32];
  const int z  = blockIdx.z;
  const int m0 = blockIdx.y * 128, n0 = blockIdx.x * 128;
  const __hip_bfloat16* X = (z == 0 ? Xq : (z == 1 ? Xk : Xv)) + (size_t)m0 * kD;
  const __hip_bfloat16* W = Wbase + (size_t)z * (kD * kD) + (size_t)n0 * kD;
  const float* bias = (z == 0 ? bq : (z == 1 ? bk : bv));
  f32x4 acc[4][4] = {};
  gemm_main(X, W, As, Bs, acc);

  const int lane = threadIdx.x & 63;
  const int wv = threadIdx.x >> 6;
  const int wr = wv >> 1, wc = wv & 1;
  short* dstQK = (short*)(z == 0 ? Qp : Kp);
  short* dstV  = (short*)Vt;
  #pragma unroll
  for (int i = 0; i < 4; ++i) {
    #pragma unroll
    for (int j = 0; j < 4; ++j) {
      #pragma unroll
      for (int r = 0; r < 4; ++r) {
        int m = m0 + wr * 64 + i * 16 + (lane >> 4) * 4 + r;
        int n = n0 + wc * 64 + j * 16 + (lane & 15);
        float y = acc[i][j][r] + bias[n];
        if (z == 0) y *= 0.125f;   // fold 1/sqrt(dk) into Q
        int b = m >> 11, sq = m & 2047, h = n >> 6, d = n & 63;
        if (z < 2)
          dstQK[((size_t)(b * 16 + h) * kS + sq) * kDK + d] = f2bf(y);
        else
          dstV[((size_t)(b * 16 + h) * kDK + d) * kS + sq] = f2bf(y);
      }
    }
  }
}

// ---------------- attention pass 1: ctx + row-sum -> rinv ----------------
// BK=64 variant (R10, best measured): barriers 64/block, two independent 32-k
// subtiles per compute phase, LDS 39.4 KB -> 4 blocks/CU.
// No global stores in the loop (R9 lesson: barrier drains vmcnt).
__global__ __launch_bounds__(256, 4) void attn_pass1(
    const __hip_bfloat16* __restrict__ Qp, const __hip_bfloat16* __restrict__ Kp,
    const __hip_bfloat16* __restrict__ Vt, __hip_bfloat16* __restrict__ Ctx,
    float* __restrict__ rinvp)
{
  __shared__ __align__(16) short Ks[2][64][68];   // [kt-row][dk], pad 68
  __shared__ __align__(16) short Vs[2][64][68];   // [d][kt-col], pad 68
  __shared__ __align__(16) short Ps[4][16][36];   // per-wave P [q][k], pad 36
  const int t = threadIdx.x;
  const int lane = t & 63;
  const int w = t >> 6;
  const int fr = lane & 15;
  const int g4 = lane >> 4;
  const int fc = g4 * 8;

  const int id  = blockIdx.x;
  const int swz = (id & 7) * 128 + (id >> 3);   // XCD-contiguous
  const int bh  = swz >> 5;
  const int q0  = (swz & 31) * 64 + w * 16;

  const __hip_bfloat16* Qh = Qp + (size_t)bh * kS * kDK;
  const __hip_bfloat16* Kh = Kp + (size_t)bh * kS * kDK;
  const __hip_bfloat16* Vh = Vt + (size_t)bh * kDK * kS;

  const short8 qf0 = *(const short8*)(Qh + (size_t)(q0 + fr) * kDK + fc);
  const short8 qf1 = *(const short8*)(Qh + (size_t)(q0 + fr) * kDK + 32 + fc);

  // staging thread mapping: 64 rows x 64 cols, each thread 2x 16B per array
  const int kr = t >> 2, kc = (t & 3) * 8;

  f32x4 ctxacc[4] = {};
  float ssumq = 0.f;                            // partial row-sum for q = fr

  short8 kA0, kA1, vA0, vA1, kB0, kB1, vB0, vB1;

#define LOAD_T(K0, K1, V0, V1, TI)                                               \
  K0 = *(const short8*)(Kh + (size_t)((TI) * 64 + kr) * kDK + kc);               \
  K1 = *(const short8*)(Kh + (size_t)((TI) * 64 + kr) * kDK + kc + 32);          \
  V0 = *(const short8*)(Vh + (size_t)kr * kS + (TI) * 64 + kc);                  \
  V1 = *(const short8*)(Vh + (size_t)kr * kS + (TI) * 64 + kc + 32);

#define STORE_T(K0, K1, V0, V1, BUF)                                             \
  *(short8*)&Ks[BUF][kr][kc]      = K0;                                          \
  *(short8*)&Ks[BUF][kr][kc + 32] = K1;                                          \
  *(short8*)&Vs[BUF][kr][kc]      = V0;                                          \
  *(short8*)&Vs[BUF][kr][kc + 32] = V1;

#define SUBT(BUF, SS)                                                            \
  {                                                                              \
    short8 k0a = *(const short8*)&Ks[BUF][(SS) * 32 + fr][fc];                   \
    short8 k0b = *(const short8*)&Ks[BUF][(SS) * 32 + fr][32 + fc];              \
    short8 k1a = *(const short8*)&Ks[BUF][(SS) * 32 + 16 + fr][fc];              \
    short8 k1b = *(const short8*)&Ks[BUF][(SS) * 32 + 16 + fr][32 + fc];         \
    f32x4 s0 = {}; s0 = MFMA16x16x32(k0a, qf0, s0); s0 = MFMA16x16x32(k0b, qf1, s0); \
    f32x4 s1 = {}; s1 = MFMA16x16x32(k1a, qf0, s1); s1 = MFMA16x16x32(k1b, qf1, s1); \
    float e00 = __expf(s0[0]), e01 = __expf(s0[1]);                              \
    float e02 = __expf(s0[2]), e03 = __expf(s0[3]);                              \
    float e10 = __expf(s1[0]), e11 = __expf(s1[1]);                              \
    float e12 = __expf(s1[2]), e13 = __expf(s1[3]);                              \
    ssumq += (e00 + e01) + (e02 + e03) + (e10 + e11) + (e12 + e13);              \
    short4v p0, p1;                                                              \
    p0.x = f2bf(e00); p0.y = f2bf(e01); p0.z = f2bf(e02); p0.w = f2bf(e03);      \
    p1.x = f2bf(e10); p1.y = f2bf(e11); p1.z = f2bf(e12); p1.w = f2bf(e13);      \
    *(short4v*)&Ps[w][fr][g4 * 4]      = p0;                                     \
    *(short4v*)&Ps[w][fr][16 + g4 * 4] = p1;                                     \
    short8 pf = *(const short8*)&Ps[w][fr][fc];                                  \
    _Pragma("unroll")                                                            \
    for (int dc = 0; dc < 4; ++dc) {                                             \
      short8 vf = *(const short8*)&Vs[BUF][dc * 16 + fr][(SS) * 32 + fc];        \
      ctxacc[dc] = MFMA16x16x32(pf, vf, ctxacc[dc]);                             \
    }                                                                            \
  }

#define COMPUTE_T(BUF) { SUBT(BUF, 0); SUBT(BUF, 1); }

  // prologue (tiles of 64 k; 32 tiles total)
  LOAD_T(kA0, kA1, vA0, vA1, 0);
  STORE_T(kA0, kA1, vA0, vA1, 0);
  LOAD_T(kB0, kB1, vB0, vB1, 1);
  __syncthreads();

  for (int i = 0; i < 32; i += 2) {
    COMPUTE_T(0);                                 // tile i
    STORE_T(kB0, kB1, vB0, vB1, 1);               // tile i+1
    if (i + 2 < 32) { LOAD_T(kA0, kA1, vA0, vA1, i + 2); }
    __syncthreads();
    COMPUTE_T(1);                                 // tile i+1
    if (i + 2 < 32) { STORE_T(kA0, kA1, vA0, vA1, 0); }
    if (i + 3 < 32) { LOAD_T(kB0, kB1, vB0, vB1, i + 3); }
    __syncthreads();
  }

  // full row-sum for q = fr: butterfly across the 4 g4 groups
  float s = ssumq;
  s += __shfl_xor(s, 16);
  s += __shfl_xor(s, 32);
  const float rvq = 1.0f / s;
  if (g4 == 0) rinvp[(size_t)bh * kS + q0 + fr] = rvq;

  // broadcast rinv for ctx rows r = g4*4+j (C-fragment row indexing)
  float rinv4[4];
  #pragma unroll
  for (int j = 0; j < 4; ++j) rinv4[j] = __shfl(rvq, g4 * 4 + j, 16);

  const int b = bh >> 4, h = bh & 15;
  #pragma unroll
  for (int dc = 0; dc < 4; ++dc) {
    #pragma unroll
    for (int j = 0; j < 4; ++j) {
      int r = g4 * 4 + j;
      float v = ctxacc[dc][j] * rinv4[j];
      ((short*)Ctx)[((size_t)(b * kS + q0 + r)) * kD + h * kDK + dc * 16 + fr] = f2bf(v);
    }
  }
#undef LOAD_T
#undef STORE_T
#undef SUBT
#undef COMPUTE_T
}

// ---------------- fused tail: o_gemm (blocks 0..255) + pass2 (blocks 256..4351)
// Both depend only on pass1; heterogeneous grid overlaps compute-bound o_gemm
// with write-bound weight streaming.
__global__ __launch_bounds__(256) void fused_tail(
    const __hip_bfloat16* __restrict__ Ctx, const __hip_bfloat16* __restrict__ Wo,
    const float* __restrict__ bo, float* __restrict__ out,
    const __hip_bfloat16* __restrict__ Qp, const __hip_bfloat16* __restrict__ Kp,
    const float* __restrict__ rinvp, float* __restrict__ Aw)
{
  __shared__ __align__(16) short As[128 * 32];
  __shared__ __align__(16) short Bs[128 * 32];
  const int t = threadIdx.x;
  const int lane = t & 63;
  const int w = t >> 6;
  const int fr = lane & 15;
  const int g4 = lane >> 4;
  const int fc = g4 * 8;

  if (blockIdx.x < 256) {
    // ---- o_gemm ----
    const int m0 = (blockIdx.x >> 3) * 128, n0 = (blockIdx.x & 7) * 128;
    f32x4 acc[4][4] = {};
    gemm_main(Ctx + (size_t)m0 * kD, Wo + (size_t)n0 * kD, As, Bs, acc);
    const int wr = w >> 1, wc = w & 1;
    #pragma unroll
    for (int i = 0; i < 4; ++i) {
      #pragma unroll
      for (int j = 0; j < 4; ++j) {
        #pragma unroll
        for (int r = 0; r < 4; ++r) {
          int m = m0 + wr * 64 + i * 16 + g4 * 4 + r;
          int n = n0 + wc * 64 + j * 16 + fr;
          __builtin_nontemporal_store(acc[i][j][r] + bo[n], &out[(size_t)m * kD + n]);
        }
      }
    }
    return;
  }

  // ---- pass2: recompute scores (swapped operands), direct C-fragment stores ----
  const int id  = blockIdx.x - 256;
  const int swz = (id & 7) * 512 + (id >> 3);
  const int bh  = swz >> 7;
  const int ksg = (swz >> 5) & 3;
  const int q0  = (swz & 31) * 64 + w * 16;
  const int k0  = ksg * 512;

  const __hip_bfloat16* Qh = Qp + (size_t)bh * kS * kDK;
  const __hip_bfloat16* Kh = Kp + (size_t)bh * kS * kDK;

  const short8 qf0 = *(const short8*)(Qh + (size_t)(q0 + fr) * kDK + fc);
  const short8 qf1 = *(const short8*)(Qh + (size_t)(q0 + fr) * kDK + 32 + fc);

  const float rvq = rinvp[(size_t)bh * kS + q0 + fr];       // this lane's q-row
  float* aw = Aw + ((size_t)bh * kS + q0 + fr) * kS;        // row base

  short8 ka[8], kb[8];

#define LOADK(ARR, KT_)                                                          \
  _Pragma("unroll")                                                              \
  for (int c = 0; c < 4; ++c) {                                                  \
    ARR[2 * c]     = *(const short8*)(Kh + (size_t)((KT_) + c * 16 + fr) * kDK + fc);      \
    ARR[2 * c + 1] = *(const short8*)(Kh + (size_t)((KT_) + c * 16 + fr) * kDK + 32 + fc); \
  }

#define CSTORE(ARR, KT_)                                                         \
  _Pragma("unroll")                                                              \
  for (int c = 0; c < 4; ++c) {                                                  \
    f32x4 st = {};                                                               \
    st = MFMA16x16x32(ARR[2 * c], qf0, st);                                      \
    st = MFMA16x16x32(ARR[2 * c + 1], qf1, st);                                  \
    f32x4 v;                                                                     \
    _Pragma("unroll")                                                            \
    for (int j = 0; j < 4; ++j) v[j] = __expf(st[j]) * rvq;                      \
    __builtin_nontemporal_store(v, (f32x4*)(aw + (KT_) + c * 16 + g4 * 4));      \
  }

  LOADK(ka, k0);
  for (int kt = k0; kt < k0 + 512; kt += 128) {
    LOADK(kb, kt + 64);
    CSTORE(ka, kt);
    if (kt + 128 < k0 + 512) { LOADK(ka, kt + 128); }
    CSTORE(kb, kt + 64);
  }
#undef LOADK
#undef CSTORE
}

extern "C" void kernel_launch(void* const* d_in, const int* in_sizes, int n_in,
                              void* d_out, int out_size, void* d_ws, size_t ws_size,
                              hipStream_t stream) {
  (void)in_sizes; (void)n_in; (void)out_size; (void)ws_size;
  const float* Qin = (const float*)d_in[0];
  const float* Kin = (const float*)d_in[1];
  const float* Vin = (const float*)d_in[2];
  const float* Wq  = (const float*)d_in[3];
  const float* bq  = (const float*)d_in[4];
  const float* Wk  = (const float*)d_in[5];
  const float* bk  = (const float*)d_in[6];
  const float* Wv  = (const float*)d_in[7];
  const float* bv  = (const float*)d_in[8];
  const float* Wo  = (const float*)d_in[9];
  const float* bo  = (const float*)d_in[10];
  __hip_bfloat16* ws = (__hip_bfloat16*)d_ws;
  float* out = (float*)d_out;
  float* rinvp = (float*)(ws + OFF_XQ);   // XQ region dead after qkv_gemm

  cvt_kernel<<<16384, 256, 0, stream>>>(Qin, Kin, Vin, Wq, Wk, Wv, Wo, ws);
  qkv_gemm<<<dim3(8, 32, 3), 256, 0, stream>>>(
      ws + OFF_XQ, ws + OFF_XK, ws + OFF_XV, ws + OFF_W, bq, bk, bv,
      ws + OFF_QP, ws + OFF_KP, ws + OFF_VT);
  attn_pass1<<<1024, 256, 0, stream>>>(
      ws + OFF_QP, ws + OFF_KP, ws + OFF_VT, ws + OFF_CTX, rinvp);
  fused_tail<<<4352, 256, 0, stream>>>(
      ws + OFF_CTX, ws + OFF_W + 3 * 1048576, bo, out,
      ws + OFF_QP, ws + OFF_KP, rinvp, out + 4194304);
}